// Round 5
// baseline (107.388 us; speedup 1.0000x reference)
//
#include <hip/hip_runtime.h>

// PINN beam residual: 1->16->16->2 tanh MLP with analytic 1st/2nd/3rd
// derivatives w.r.t. the scalar input. Outputs (u, w, wx, N, M, Q) concat.
//
// R1: hw tanh (exp2+rcp)       -> 50us, VALU-issue-bound.
// R2: v_pk_fma_f32 j-pairs     -> 44.6us; pk works but compiler reg-capped
//     (VGPR 56 vs ~128 needed) -> spill stalls, VALUBusy 60%.
// R3: 2 pts/thread in pk halves-> 42.4us; same story (VGPR 84 vs ~190).
// R4: 1 pt/thread, DERIVATIVE-packed: AB0[i]={a,a'}, AB1[i]={a'',a'''}
//     (64 VGPRs), per-j accumulators {z,z'} / {z'',z'''} -> 2 pkfma per
//     (i,j). Live set ~105 regs; __launch_bounds__(256,4) caps at 128 so
//     no spills at 4 waves/SIMD. Head accums packed as {u,w},{u',w'}.

typedef float v2f __attribute__((ext_vector_type(2)));
typedef float v4f __attribute__((ext_vector_type(4)));

constexpr float EA_CONST = 1000.0f;
constexpr float EI_CONST = 100.0f;
constexpr float TWO_LOG2E = 2.8853900817779268f;

__device__ __forceinline__ v2f splat2(float s) { v2f r; r.x = s; r.y = s; return r; }
__device__ __forceinline__ v2f pkfma(v2f a, v2f b, v2f c) {
    return __builtin_elementwise_fma(a, b, c);
}

__device__ __forceinline__ float fast_tanh(float x) {
    float e = __builtin_amdgcn_exp2f(x * TWO_LOG2E);
    float r = __builtin_amdgcn_rcpf(1.0f + e);
    return fmaf(-2.0f, r, 1.0f);
}

__global__ __launch_bounds__(256, 4) void pinn_kernel(
    const float* __restrict__ x,
    const float* __restrict__ W1, const float* __restrict__ b1,
    const float* __restrict__ W2, const float* __restrict__ b2,
    const float* __restrict__ W3, const float* __restrict__ b3,
    float* __restrict__ out, int n)
{
    // sL1[i] = {c_i, -2c^2, -2c^3, b1_i};  sJC[j] = {W3[0][j], W3[1][j], b2[j], 0}
    __shared__ v4f sL1[16];
    __shared__ v4f sJC[16];
    __shared__ float sW2[256];
    __shared__ float sb3[2];
    {
        int t = threadIdx.x;
        if (t < 16) {
            float c = W1[t] * 0.5f;            // W1_i / L, L = 2
            v4f l1; l1.x = c; l1.y = -2.0f * c * c; l1.z = -2.0f * c * c * c; l1.w = b1[t];
            sL1[t] = l1;
            v4f jc; jc.x = W3[t]; jc.y = W3[16 + t]; jc.z = b2[t]; jc.w = 0.0f;
            sJC[t] = jc;
        }
        sW2[t] = W2[t];
        if (t < 2) sb3[t] = b3[t];
    }
    __syncthreads();

    int idx = blockIdx.x * blockDim.x + threadIdx.x;
    if (idx >= n) return;

    float xr = x[idx];

    // ---- Layer 1: AB0[i] = {a, a'},  AB1[i] = {a'', a'''} ----
    v2f AB0[16], AB1[16];
#pragma unroll
    for (int i = 0; i < 16; ++i) {
        v4f l1 = sL1[i];
        float c = l1.x, k2 = l1.y, k3 = l1.z, bb = l1.w;
        float t  = fast_tanh(fmaf(c, xr, bb));
        float t2 = t * t;
        float p  = 1.0f - t2;
        float tp = t * p;
        float g  = fmaf(-3.0f, t2, 1.0f);
        v2f ab0; ab0.x = t;       ab0.y = p * c;
        v2f ab1; ab1.x = tp * k2; ab1.y = (p * g) * k3;
        AB0[i] = ab0;
        AB1[i] = ab1;
    }

    // ---- Layer 2 + head, fused per output unit j ----
    v2f UW   = splat2(0.0f);   // {u, w}
    v2f UWp  = splat2(0.0f);   // {u', w'}
    v2f Wpp2 = splat2(0.0f);   // {w'' acc, w''' acc}
#pragma unroll
    for (int j = 0; j < 16; ++j) {
        const v4f* row = (const v4f*)(sW2 + j * 16);
        v4f r0 = row[0], r1 = row[1], r2 = row[2], r3 = row[3];
        v4f jc = sJC[j];
        v2f acc0; acc0.x = jc.z; acc0.y = 0.0f;   // {z, z'}
        v2f acc1 = splat2(0.0f);                   // {z'', z'''}
        float wr[16] = { r0.x, r0.y, r0.z, r0.w, r1.x, r1.y, r1.z, r1.w,
                         r2.x, r2.y, r2.z, r2.w, r3.x, r3.y, r3.z, r3.w };
#pragma unroll
        for (int i = 0; i < 16; ++i) {
            v2f wv = splat2(wr[i]);
            acc0 = pkfma(wv, AB0[i], acc0);
            acc1 = pkfma(wv, AB1[i], acc1);
        }
        float z = acc0.x, zp = acc0.y, zpp = acc1.x, zppp = acc1.y;
        float t  = fast_tanh(z);
        float t2 = t * t;
        float p  = 1.0f - t2;
        float tp = t * p;
        float g  = fmaf(-3.0f, t2, 1.0f);
        // pd = {p*zpp, p*zppp}
        v2f pd = splat2(p) * acc1;
        float zp2   = zp * zp;
        float a2p   = p * zp;
        float a2pp  = fmaf(-2.0f * tp, zp2, pd.x);
        float m1    = fmaf(-6.0f * tp, zp * zpp, pd.y);
        float a2ppp = fmaf(-2.0f * (p * g), zp2 * zp, m1);
        v2f w3v; w3v.x = jc.x; w3v.y = jc.y;       // {W3[0][j], W3[1][j]}
        UW   = pkfma(w3v, splat2(t),   UW);
        UWp  = pkfma(w3v, splat2(a2p), UWp);
        v2f d23; d23.x = a2pp; d23.y = a2ppp;
        Wpp2 = pkfma(splat2(jc.y), d23, Wpp2);     // {w'', w'''}
    }

    float u    = UW.x + sb3[0];
    float w    = UW.y + sb3[1];
    float up   = UWp.x;
    float wp   = UWp.y;
    float wpp  = Wpp2.x;
    float wppp = Wpp2.y;

    float Nax = EA_CONST * fmaf(0.5f * wp, wp, up);
    out[idx]         = u;
    out[n + idx]     = w;
    out[2 * n + idx] = wp;
    out[3 * n + idx] = Nax;
    out[4 * n + idx] = -EI_CONST * wpp;
    out[5 * n + idx] = fmaf(Nax, wp, -EI_CONST * wppp);
}

extern "C" void kernel_launch(void* const* d_in, const int* in_sizes, int n_in,
                              void* d_out, int out_size, void* d_ws, size_t ws_size,
                              hipStream_t stream) {
    const float* x  = (const float*)d_in[0];
    const float* W1 = (const float*)d_in[1];
    const float* b1 = (const float*)d_in[2];
    const float* W2 = (const float*)d_in[3];
    const float* b2 = (const float*)d_in[4];
    const float* W3 = (const float*)d_in[5];
    const float* b3 = (const float*)d_in[6];
    float* out = (float*)d_out;

    int n = in_sizes[0];
    int block = 256;
    int grid = (n + block - 1) / block;
    pinn_kernel<<<grid, block, 0, stream>>>(x, W1, b1, W2, b2, W3, b3, out, n);
}

// Round 6
// 105.004 us; speedup vs baseline: 1.0227x; 1.0227x over previous
//
#include <hip/hip_runtime.h>

// PINN beam residual: 1->16->16->2 tanh MLP with analytic 1st/2nd/3rd
// derivatives w.r.t. the scalar input. Outputs (u, w, wx, N, M, Q) concat.
//
// R1: hw tanh (exp2+rcp)        -> 50us, VALU 95%.
// R2-R4: packed fp32 variants   -> 42-49us; pkfma halved FMA issue but all
//   three used indexed local arrays (wr[16], AB[16], z2[16]) which the
//   compiler demoted to scratch: VGPR_Count 56-84 vs >=64 mandatory live,
//   ~2x instruction bloat (spill/reload movs), VALUBusy stuck 60-72%.
// R5: zero local arrays, zero LDS. 32 NAMED v2f hold layer-1 {a,a'} and
//   {a'',a'''}; all weights read straight from global with wave-uniform
//   addresses -> s_load_dwordx16 to SGPRs (free broadcast into VOP3P).
//   Pure straight-line code; nothing the compiler can demote.

typedef float v2f __attribute__((ext_vector_type(2)));

constexpr float EA_CONST = 1000.0f;
constexpr float EI_CONST = 100.0f;
constexpr float TWO_LOG2E = 2.8853900817779268f;

__device__ __forceinline__ v2f splat2(float s) { v2f r; r.x = s; r.y = s; return r; }
__device__ __forceinline__ v2f pkfma(v2f a, v2f b, v2f c) {
    return __builtin_elementwise_fma(a, b, c);
}
__device__ __forceinline__ float fast_tanh(float x) {
    float e = __builtin_amdgcn_exp2f(x * TWO_LOG2E);
    float r = __builtin_amdgcn_rcpf(1.0f + e);
    return fmaf(-2.0f, r, 1.0f);
}

__global__ __launch_bounds__(256) void pinn_kernel(
    const float* __restrict__ x,
    const float* __restrict__ W1, const float* __restrict__ b1,
    const float* __restrict__ W2, const float* __restrict__ b2,
    const float* __restrict__ W3, const float* __restrict__ b3,
    float* __restrict__ out, int n)
{
    int idx = blockIdx.x * blockDim.x + threadIdx.x;
    if (idx >= n) return;
    float xr = x[idx];

    // ---- Layer 1: AB0_i = {a, a'}, AB1_i = {a'', a'''} (named, no arrays) ----
#define L1(i)                                                              \
    v2f AB0_##i, AB1_##i;                                                  \
    {                                                                      \
        float c  = W1[i] * 0.5f;              /* W1_i / L, L = 2 */        \
        float t  = fast_tanh(fmaf(c, xr, b1[i]));                          \
        float t2 = t * t;                                                  \
        float p  = 1.0f - t2;                                              \
        float tp = t * p;                                                  \
        float c2 = c * c;                                                  \
        float g  = fmaf(-3.0f, t2, 1.0f);                                  \
        AB0_##i.x = t;                                                     \
        AB0_##i.y = p * c;                                                 \
        AB1_##i.x = tp * c2 * -2.0f;                                       \
        AB1_##i.y = (p * g) * (c2 * c) * -2.0f;                            \
    }
    L1(0)  L1(1)  L1(2)  L1(3)  L1(4)  L1(5)  L1(6)  L1(7)
    L1(8)  L1(9)  L1(10) L1(11) L1(12) L1(13) L1(14) L1(15)
#undef L1

    // ---- Layer 2 + head, fused per output unit j ----
    v2f UW   = splat2(0.0f);   // {u, w}
    v2f UWp  = splat2(0.0f);   // {u', w'}
    v2f Wd23 = splat2(0.0f);   // {w'', w'''}

#define ACC(i, j)                                                          \
    {                                                                      \
        v2f wv = splat2(W2[(j) * 16 + (i)]);  /* uniform -> SGPR */        \
        acc0 = pkfma(wv, AB0_##i, acc0);                                   \
        acc1 = pkfma(wv, AB1_##i, acc1);                                   \
    }

#define JBODY(j)                                                           \
    {                                                                      \
        v2f acc0; acc0.x = b2[j]; acc0.y = 0.0f;  /* {z, z'} */            \
        v2f acc1 = splat2(0.0f);                   /* {z'', z'''} */       \
        ACC(0, j)  ACC(1, j)  ACC(2, j)  ACC(3, j)                         \
        ACC(4, j)  ACC(5, j)  ACC(6, j)  ACC(7, j)                         \
        ACC(8, j)  ACC(9, j)  ACC(10, j) ACC(11, j)                        \
        ACC(12, j) ACC(13, j) ACC(14, j) ACC(15, j)                        \
        float z = acc0.x, zp = acc0.y, zpp = acc1.x, zppp = acc1.y;        \
        float t  = fast_tanh(z);                                           \
        float t2 = t * t;                                                  \
        float p  = 1.0f - t2;                                              \
        float tp = t * p;                                                  \
        float g  = fmaf(-3.0f, t2, 1.0f);                                  \
        float a2p   = p * zp;                                              \
        float zp2   = zp * zp;                                             \
        float a2pp  = fmaf(-2.0f * tp, zp2, p * zpp);                      \
        float a2ppp = fmaf(-2.0f * (p * g), zp2 * zp,                      \
                           fmaf(-6.0f * tp, zp * zpp, p * zppp));          \
        float w30 = W3[j], w31 = W3[16 + j];                               \
        v2f w3v; w3v.x = w30; w3v.y = w31;                                 \
        UW  = pkfma(w3v, splat2(t),   UW);                                 \
        UWp = pkfma(w3v, splat2(a2p), UWp);                                \
        v2f d23; d23.x = a2pp; d23.y = a2ppp;                              \
        Wd23 = pkfma(splat2(w31), d23, Wd23);                              \
    }
    JBODY(0)  JBODY(1)  JBODY(2)  JBODY(3)
    JBODY(4)  JBODY(5)  JBODY(6)  JBODY(7)
    JBODY(8)  JBODY(9)  JBODY(10) JBODY(11)
    JBODY(12) JBODY(13) JBODY(14) JBODY(15)
#undef JBODY
#undef ACC

    float u    = UW.x + b3[0];
    float w    = UW.y + b3[1];
    float up   = UWp.x;
    float wp   = UWp.y;
    float wpp  = Wd23.x;
    float wppp = Wd23.y;

    float Nax = EA_CONST * fmaf(0.5f * wp, wp, up);
    out[idx]         = u;
    out[n + idx]     = w;
    out[2 * n + idx] = wp;
    out[3 * n + idx] = Nax;
    out[4 * n + idx] = -EI_CONST * wpp;
    out[5 * n + idx] = fmaf(Nax, wp, -EI_CONST * wppp);
}

extern "C" void kernel_launch(void* const* d_in, const int* in_sizes, int n_in,
                              void* d_out, int out_size, void* d_ws, size_t ws_size,
                              hipStream_t stream) {
    const float* x  = (const float*)d_in[0];
    const float* W1 = (const float*)d_in[1];
    const float* b1 = (const float*)d_in[2];
    const float* W2 = (const float*)d_in[3];
    const float* b2 = (const float*)d_in[4];
    const float* W3 = (const float*)d_in[5];
    const float* b3 = (const float*)d_in[6];
    float* out = (float*)d_out;

    int n = in_sizes[0];
    int block = 256;
    int grid = (n + block - 1) / block;
    pinn_kernel<<<grid, block, 0, stream>>>(x, W1, b1, W2, b2, W3, b3, out, n);
}